// Round 8
// baseline (103.568 us; speedup 1.0000x reference)
//
#include <hip/hip_runtime.h>
#include <math.h>

#define NB 32
#define CC 64
#define LL 1024
#define EPS 1e-6f
#define SCALE 14.42695040888963f   // 10*log2(e): exp(10*s) == exp2(SCALE*s)

typedef __attribute__((ext_vector_type(8))) __bf16 bf16x8;
typedef __attribute__((ext_vector_type(4))) float f32x4;

// DPP helpers: 16-lane butterfly on the VALU pipe (NOT ds_bpermute).
// 0xB1=quad_perm(1,0,3,2) [xor1], 0x4E=quad_perm(2,3,0,1) [xor2],
// 0x141=row_half_mirror [xor4 within 8], 0x140=row_mirror [xor8 within 16].
// Verified end-to-end in round 6 (passed, absmax 0.0).
template <int CTRL>
__device__ __forceinline__ float dppf(float x) {
    return __int_as_float(__builtin_amdgcn_update_dpp(
            0, __float_as_int(x), CTRL, 0xF, 0xF, true));
}
template <int CTRL>
__device__ __forceinline__ unsigned dppu(unsigned x) {
    return (unsigned)__builtin_amdgcn_update_dpp(
            0, (int)x, CTRL, 0xF, 0xF, true);
}

// ws byte layout:
//   At      @ 0         (4 MB)   bf16 [32][1024][64]  rgb, normalized*SCALE, [l][c]
//   Bt      @ 4194304   (4 MB)   bf16 [32][1024][64]  ir, normalized, [l][c]
//   row_sum @ 8388608   (128 KB) f32[32768]   (final, written by merge)
//   col_sum @ 8519680   (128 KB) f32[32768]
//   row_pk  @ 8650752   (128 KB) u32[32768]  (expbits&~1023)|(1023-j)
//   col_pk  @ 8781824   (128 KB) u32[32768]  (expbits&~1023)|(1023-i)
//   partial @ 8912896   (256 B)  f32[64] loss partials
//   rxp     @ 16777216  (16 MB)  float2 [32 jq][32768]    row (sum, pk) partials
//   cxp     @ 33554432  (4 MB)   float2 [32 bb][16 it][1024] col (sum, pk) partials
// No zero-init needed: every scratch word is direct-stored exactly once.

__global__ __launch_bounds__(256) void transpose_norm_kernel(
        const float* __restrict__ rgb, const float* __restrict__ ir,
        __bf16* __restrict__ At, __bf16* __restrict__ Bt) {
    __shared__ float tile[64][65];
    __shared__ float red[4][64];
    __shared__ float rn[64];

    const int t   = threadIdx.x;
    const int blk = blockIdx.x;
    const int in  = blk >> 9;
    const int b   = (blk >> 4) & 31;
    const int l0  = (blk & 15) << 6;
    const float* src = in ? ir : rgb;
    __bf16*      dst = in ? Bt : At;
    const float  sc  = in ? 1.0f : SCALE;   // fold exp2 prescale into rgb side

    const int lv = (t & 15) << 2;   // l within tile, step 4
    const int cv = t >> 4;          // c base lane, 0..15
    const float* sp = src + ((size_t)b << 16) + l0 + lv;
#pragma unroll
    for (int u = 0; u < 4; ++u) {
        int c = cv + (u << 4);
        float4 v = *(const float4*)(sp + ((size_t)c << 10));
        tile[c][lv + 0] = v.x;
        tile[c][lv + 1] = v.y;
        tile[c][lv + 2] = v.z;
        tile[c][lv + 3] = v.w;
    }
    __syncthreads();

    const int ll = t & 63, cg = t >> 6;
    float ssq = 0.f;
#pragma unroll
    for (int u = 0; u < 16; ++u) {
        float v = tile[cg * 16 + u][ll];
        ssq = fmaf(v, v, ssq);
    }
    red[cg][ll] = ssq;
    __syncthreads();
    if (t < 64) {
        float s = red[0][t] + red[1][t] + red[2][t] + red[3][t];
        rn[t] = sc / fmaxf(sqrtf(s), 1e-12f);
    }
    __syncthreads();

    const int lw  = t >> 2;
    const int cg2 = t & 3;
    const float r = rn[lw];
    bf16x8 v0, v1;
#pragma unroll
    for (int u = 0; u < 8; ++u)
        v0[u] = (__bf16)(tile[cg2 * 16 + u][lw] * r);
#pragma unroll
    for (int u = 0; u < 8; ++u)
        v1[u] = (__bf16)(tile[cg2 * 16 + 8 + u][lw] * r);
    size_t base = ((((size_t)b << 10) + l0 + lw) << 6) + cg2 * 16;
    *(bf16x8*)(dst + base)     = v0;
    *(bf16x8*)(dst + base + 8) = v1;
}

// Single-pass GEMM, ZERO-SYNC edition. r0-r13 post-mortem: every variant
// (two-pass, dbuf, full-resident, wave-exclusive) used global_load_lds
// staging + per-chunk __syncthreads -> a full vmcnt(0)+lgkmcnt(0) drain in
// wave-lockstep every ~600 cy of issue; all landed gemm in [30,40] us vs a
// ~8 us pipe floor. The staging is pointless anyway: inputs are 8 MB
// (L2/L3-resident) and the B-fragment pattern (16 rows x 128 B per wave
// load = 16 full 64-B lines) is as coalesced from L2 as from LDS.
//
// r14: wave owns 64i x 32j. A held in 8 reg frags (loaded once). B streamed
// directly from global: 4 x global_load_dwordx4 per wave TOTAL. No LDS, no
// global_load_lds, no __syncthreads -- waves fully independent, 16 waves/CU
// of TLP hide L2 latency. Row stats: registers + DPP m-fold (verified r12),
// per-wave partials (32/row) -> rxp. Col stats: in-register g-fold + 8
// shfl_xor total, one partial per (bb,it,j) -> cxp.
// Grid 4096 = bb(32) x it(16) x jqq(8); wave w takes jq = jqq*4+w.
__global__ __launch_bounds__(256) void gemm_stats_kernel(
        const __bf16* __restrict__ At, const __bf16* __restrict__ Bt,
        float2* __restrict__ rxp, float2* __restrict__ cxp) {
    const int t   = threadIdx.x;
    const int blk = blockIdx.x;
    const int jqq = blk & 7;
    const int it  = (blk >> 3) & 15;
    const int bb  = blk >> 7;
    const int i0  = it << 6;
    const int w = t >> 6, lane = t & 63;
    const int m = lane & 15, q = lane >> 4;
    const int jq = (jqq << 2) + w;          // 0..31, wave-exclusive

    const size_t bbase = (size_t)bb << 16;

    // A fragments for all 4 row-groups: row = i0+16g+m, k-halves q*8 (+32).
    bf16x8 a[4][2];
#pragma unroll
    for (int g = 0; g < 4; ++g) {
        const __bf16* Ap = At + bbase + ((size_t)(i0 + 16 * g + m) << 6) + q * 8;
        a[g][0] = *(const bf16x8*)(Ap);
        a[g][1] = *(const bf16x8*)(Ap + 32);
    }

    float    rsum[4][4];
    unsigned rpk[4][4];
#pragma unroll
    for (int g = 0; g < 4; ++g)
#pragma unroll
        for (int r = 0; r < 4; ++r) { rsum[g][r] = 0.f; rpk[g][r] = 0u; }

    // col-pack base: iinv = 1023 - (i0+16g+4q+r) = (Kb - 16g) - r.
    const unsigned Kb = 1023u - (unsigned)(i0 + 4 * q);

#pragma unroll
    for (int ct = 0; ct < 2; ++ct) {
        // B fragment straight from global: col j = jq*32+ct*16+m, k = q*8.
        const int j = (jq << 5) + (ct << 4) + m;
        const __bf16* bp = Bt + bbase + ((size_t)j << 6) + q * 8;
        bf16x8 b0 = *(const bf16x8*)(bp);
        bf16x8 b1 = *(const bf16x8*)(bp + 32);

        const unsigned jinv = 1023u - (unsigned)j;
        float csv = 0.f;
        unsigned pcv = 0u;
#pragma unroll
        for (int g = 0; g < 4; ++g) {
            f32x4 acc = (f32x4){0.f, 0.f, 0.f, 0.f};
            acc = __builtin_amdgcn_mfma_f32_16x16x32_bf16(a[g][0], b0, acc, 0, 0, 0);
            acc = __builtin_amdgcn_mfma_f32_16x16x32_bf16(a[g][1], b1, acc, 0, 0, 0);
            // C/D layout (verified r2-r6): row = i0+16g+4q+r, col = j.
            const unsigned Kg = Kb - 16u * (unsigned)g;
#pragma unroll
            for (int r = 0; r < 4; ++r) {
                float e = __builtin_amdgcn_exp2f(acc[r]);   // SCALE in At
                unsigned eb = __float_as_uint(e) & 0xFFFFFC00u;
                rsum[g][r] += e;
                unsigned pr = eb | jinv;
                if (pr > rpk[g][r]) rpk[g][r] = pr;         // v_max_u32
                unsigned pc = eb + (Kg - (unsigned)r);      // == eb | iinv
                if (g == 0 && r == 0) { csv = e; pcv = pc; }
                else { csv += e; if (pc > pcv) pcv = pc; }
            }
        }
        // Col fold: rows 16g+4q+r folded in-register above (g,r); fold the
        // q groups with xor16+xor32 shfl (4 per ct -- 8 total per wave).
        csv += __shfl_xor(csv, 16, 64);
        csv += __shfl_xor(csv, 32, 64);
        unsigned o = (unsigned)__shfl_xor((int)pcv, 16, 64);
        if (o > pcv) pcv = o;
        o = (unsigned)__shfl_xor((int)pcv, 32, 64);
        if (o > pcv) pcv = o;
        if (q == 0) {
            float2 v; v.x = csv; v.y = __uint_as_float(pcv);
            cxp[(((bb << 4) + it) << 10) + j] = v;   // (bb,it,j) unique
        }
    }

    // Row fold: m-butterfly on the VALU pipe via DPP; lanes m==0 store this
    // wave's 32-j partials for rows i0+16g+4q+r -> rxp[jq][bb*1024 + i].
    const int ribase = (jq << 15) + (bb << 10) + i0 + (q << 2);
#pragma unroll
    for (int g = 0; g < 4; ++g)
#pragma unroll
        for (int r = 0; r < 4; ++r) {
            float s = rsum[g][r];
            s += dppf<0xB1>(s);
            s += dppf<0x4E>(s);
            s += dppf<0x141>(s);
            s += dppf<0x140>(s);
            unsigned p = rpk[g][r];
            unsigned o;
            o = dppu<0xB1>(p);  if (o > p) p = o;
            o = dppu<0x4E>(p);  if (o > p) p = o;
            o = dppu<0x141>(p); if (o > p) p = o;
            o = dppu<0x140>(p); if (o > p) p = o;
            if (m == 0) {
                float2 v; v.x = s; v.y = __uint_as_float(p);
                rxp[ribase + (g << 4) + r] = v;
            }
        }
}

// Fold row partials (32 jq) and col partials (16 i-tiles) into the final
// stats arrays. Tie-break: umax on packed (bits|inv_index) keeps the
// smaller index on equal truncated value = first-occurrence, matching ref.
__global__ __launch_bounds__(256) void merge_kernel(
        const float2* __restrict__ rxp, const float2* __restrict__ cxp,
        float* __restrict__ row_sum, unsigned* __restrict__ row_pk,
        float* __restrict__ col_sum, unsigned* __restrict__ col_pk) {
    int p = blockIdx.x * 256 + threadIdx.x;   // 0..32767
    // rows: 32 partials, stride 32768 float2s (lane-coalesced per k)
    float rs = 0.f;
    unsigned rp = 0u;
#pragma unroll
    for (int k = 0; k < 32; ++k) {
        float2 v = rxp[(k << 15) + p];
        rs += v.x;
        unsigned o = __float_as_uint(v.y);
        if (o > rp) rp = o;
    }
    row_sum[p] = rs;
    row_pk[p]  = rp;
    // cols: 16 partials, stride 1024 float2s
    int bb = p >> 10, j = p & 1023;
    float cs = 0.f;
    unsigned cp = 0u;
#pragma unroll
    for (int k = 0; k < 16; ++k) {
        float2 v = cxp[(bb << 14) + (k << 10) + j];
        cs += v.x;
        unsigned o = __float_as_uint(v.y);
        if (o > cp) cp = o;
    }
    col_sum[p] = cs;
    col_pk[p]  = cp;
}

// Reference broadcasting: trailing /(sum+EPS) factors are indexed by ELEMENT
// position, not by argmax. Writes per-block partials (no atomics, no init).
__global__ __launch_bounds__(256) void loss_kernel2(
        const float* __restrict__ row_sum, const unsigned* __restrict__ row_pk,
        const float* __restrict__ col_sum, const unsigned* __restrict__ col_pk,
        float* __restrict__ partial) {
    int t = blockIdx.x * 256 + threadIdx.x;
    float acc = 0.f;
#pragma unroll
    for (int it = 0; it < 4; ++it) {
        int p = t + it * 16384;
        if (p < NB * LL) {
            unsigned pk2 = row_pk[p];
            float m2 = __uint_as_float(pk2 & 0xFFFFFC00u);
            int j = 1023 - (int)(pk2 & 1023u);
            float s2 = row_sum[p];
            float s1 = col_sum[p];
            unsigned pk1 = col_pk[(p & ~1023) + j];
            float m1 = __uint_as_float(pk1 & 0xFFFFFC00u);
            acc += logf((m2 / (s2 + EPS)) * (m1 / (s1 + EPS)));
        } else {
            int p2 = p - NB * LL;
            unsigned pk1 = col_pk[p2];
            float m1 = __uint_as_float(pk1 & 0xFFFFFC00u);
            int i = 1023 - (int)(pk1 & 1023u);
            float s1 = col_sum[p2];
            float s2 = row_sum[p2];
            unsigned pk2 = row_pk[(p2 & ~1023) + i];
            float m2 = __uint_as_float(pk2 & 0xFFFFFC00u);
            acc += logf((m1 / (s1 + EPS)) * (m2 / (s2 + EPS)));
        }
    }
#pragma unroll
    for (int off = 32; off > 0; off >>= 1) acc += __shfl_down(acc, off, 64);
    __shared__ float wsum[4];
    int lane = threadIdx.x & 63, w = threadIdx.x >> 6;
    if (lane == 0) wsum[w] = acc;
    __syncthreads();
    if (threadIdx.x == 0)
        partial[blockIdx.x] = wsum[0] + wsum[1] + wsum[2] + wsum[3];
}

__global__ void finalize_kernel(const float* __restrict__ partial,
                                float* __restrict__ out) {
    float v = partial[threadIdx.x];
#pragma unroll
    for (int off = 32; off > 0; off >>= 1) v += __shfl_down(v, off, 64);
    if (threadIdx.x == 0) out[0] = -v / (float)(2 * NB * LL);
}

extern "C" void kernel_launch(void* const* d_in, const int* in_sizes, int n_in,
                              void* d_out, int out_size, void* d_ws, size_t ws_size,
                              hipStream_t stream) {
    const float* rgb = (const float*)d_in[0];
    const float* ir  = (const float*)d_in[1];
    char* wsb = (char*)d_ws;

    __bf16*   At      = (__bf16*)(wsb);
    __bf16*   Bt      = (__bf16*)(wsb + 4194304);
    float*    row_sum = (float*)(wsb + 8388608);
    float*    col_sum = (float*)(wsb + 8519680);
    unsigned* row_pk  = (unsigned*)(wsb + 8650752);
    unsigned* col_pk  = (unsigned*)(wsb + 8781824);
    float*    partial = (float*)(wsb + 8912896);
    float2*   rxp     = (float2*)(wsb + 16777216);
    float2*   cxp     = (float2*)(wsb + 33554432);

    transpose_norm_kernel<<<1024, 256, 0, stream>>>(rgb, ir, At, Bt);
    gemm_stats_kernel<<<4096, 256, 0, stream>>>(At, Bt, rxp, cxp);
    merge_kernel<<<128, 256, 0, stream>>>(rxp, cxp,
                                          row_sum, row_pk, col_sum, col_pk);
    loss_kernel2<<<64, 256, 0, stream>>>(row_sum, row_pk, col_sum, col_pk, partial);
    finalize_kernel<<<1, 64, 0, stream>>>(partial, (float*)d_out);
}